// Round 5
// baseline (497.587 us; speedup 1.0000x reference)
//
#include <hip/hip_runtime.h>
#include <hip/hip_cooperative_groups.h>

namespace cg = cooperative_groups;

#define N_NODES 100000
#define N_EDGES 3200000
#define BATCH 16384
#define MAX_SLOTS 32768

// Nibble-packed degree histogram: 100K nodes x 4 bit = 50 KB LDS.
#define NW 12500       // words (8 nodes/word)
#define SLICES 256
#define EPS2 12500     // edges per slice
#define I4PS2 3125

// Bucket machinery: 256 buckets x 128 slots.
#define NBUCK 256
#define BCAP 8192      // entries per bucket region; mean fill 3513 -> +33 sigma
#define BCAP_SH 13
#define EBCAP 4608     // per-block LDS staging; mean 3513 -> +22 sigma

#define NTHREADS 512
#define NBLOCKS 256
#define GSIZE (NTHREADS * NBLOCKS)

// Workspace layout (byte offsets, 16B aligned). ws_size = 256 MiB.
#define OFF_SLOT      0          // 100000 u32
#define OFF_DINV      400000     // 100000 f32
#define OFF_NODELIST  800000     // 32768 ints
#define OFF_GCUR      931072     // 256 u32 bucket cursors
#define OFF_PARTIALS  932096     // 256 x 12500 words = 12.8 MB
#define OFF_WH        13732096   // bf16(w), 100000x64x2 B = 12.8 MB (NO dinv folded)
#define OFF_BINS      26532096   // packed (slot<<17|src), 256 x 8192 x 4 B = 8 MB
#define OFF_EMB       34920704   // bf16 32768x64

__device__ __forceinline__ unsigned bfr(float f) {   // fp32 -> bf16 bits, RNE
    unsigned u = __float_as_uint(f);
    return (u + 0x7FFFu + ((u >> 16) & 1u)) >> 16;
}
__device__ __forceinline__ float bfx(unsigned h) {   // low 16 bits -> fp32
    return __uint_as_float(h << 16);
}

__device__ __forceinline__ int cert(int d, const unsigned* __restrict__ slot,
                                    const int* __restrict__ nodelist) {
    unsigned r = slot[d];
    unsigned idx = r - 1u;
    if (idx < (unsigned)MAX_SLOTS && nodelist[idx] == d) return (int)idx;
    return -1;
}

// Phase-overlaid LDS: P1 hist+staging (70.5 KB) / P2 reduction (8 KB) /
// P3 sort buffer (33.8 KB). One block/CU; phases separated by grid.sync.
union SharedU {
    struct { unsigned h[NW]; unsigned ebuf[EBCAP]; int lc[NBUCK]; int base[NBUCK]; int ecnt; } p1;
    struct { unsigned pA[NTHREADS], pB[NTHREADS], pC[NTHREADS], pD[NTHREADS]; } p2;
    struct { unsigned ebuf2[BCAP]; int lc[128]; int st[128]; } p3;
};

// ONE cooperative launch replacing 5 serial kernels (r4 lesson: every kernel
// individually < 41us; the remaining cost is launch gaps + zero overlap of
// independent streams). Phases:
//   P0 slot/nodelist/gcur init
//   P1 nibble degree hist + cert + LDS-staged compact scatter (r4's measured-
//      good atomic discipline) + w->bf16 conversion folded in (independent
//      stream, overlaps the LDS-bound histogram across waves)
//   P2 partials reduction -> dinv only (tiny now)
//   P3 per-bucket counting sort (1 block/bucket, dedup'd vs r4's 4x) + gather
//      with per-edge dinv[src] (f32 mult, f64 accumulate: race-ordered edge
//      lists stay bit-stable)
//   P4 FM pairwise + linear
__global__ void __launch_bounds__(NTHREADS, 1)
k_mega(const int* __restrict__ pairs, unsigned* __restrict__ slot,
       int* __restrict__ nodelist, unsigned* __restrict__ gcur,
       const int* __restrict__ src, const int* __restrict__ dst,
       unsigned* __restrict__ partials, unsigned* __restrict__ bins,
       const float4* __restrict__ w4, float* __restrict__ dinv,
       uint4* __restrict__ wh4, const float4* __restrict__ bias4,
       uint4* __restrict__ emb4, const float* __restrict__ lw,
       const float* __restrict__ lb, float* __restrict__ out) {
    __shared__ SharedU su;
    cg::grid_group grid = cg::this_grid();
    const int tid = threadIdx.x;
    const int gtid = blockIdx.x * NTHREADS + tid;
    const int lane = tid & 63;

    // ---------------- P0: flags ----------------
    if (gtid < NBUCK) gcur[gtid] = (unsigned)(gtid << BCAP_SH);
    if (gtid < 2 * BATCH) {
        int n = pairs[gtid];
        nodelist[gtid] = n;
        slot[n] = (unsigned)(gtid + 1);
    }
    __threadfence();
    grid.sync();

    // ---------------- P1: hist + stage + flush + w->bf16 ----------------
    {
        int g = blockIdx.x;
        for (int i = tid; i < NW; i += NTHREADS) su.p1.h[i] = 0;
        if (tid < NBUCK) su.p1.lc[tid] = 0;
        if (tid == 0) su.p1.ecnt = 0;
        __syncthreads();
        const int4* d4 = (const int4*)(dst + g * EPS2);
        const int4* s4 = (const int4*)(src + g * EPS2);
        for (int i = tid; i < I4PS2; i += NTHREADS) {
            int4 v = d4[i];
            int4 s = s4[i];
            atomicAdd(&su.p1.h[v.x >> 3], 1u << ((v.x & 7) << 2));
            atomicAdd(&su.p1.h[v.y >> 3], 1u << ((v.y & 7) << 2));
            atomicAdd(&su.p1.h[v.z >> 3], 1u << ((v.z & 7) << 2));
            atomicAdd(&su.p1.h[v.w >> 3], 1u << ((v.w & 7) << 2));
#define STAGE(dc, sc)                                                          \
            {                                                                  \
                int t = cert(dc, slot, nodelist);                              \
                unsigned long long mk = __ballot(t >= 0);                      \
                int bs = 0;                                                    \
                if (lane == 0) bs = atomicAdd(&su.p1.ecnt, (int)__popcll(mk)); \
                bs = __shfl(bs, 0, 64);                                        \
                if (t >= 0) {                                                  \
                    int off = bs + (int)__popcll(mk & ((1ull << lane) - 1ull));\
                    if (off < EBCAP) {                                         \
                        su.p1.ebuf[off] = ((unsigned)t << 17) | (unsigned)(sc);\
                        atomicAdd(&su.p1.lc[t >> 7], 1);                       \
                    }                                                          \
                }                                                              \
            }
            STAGE(v.x, s.x)
            STAGE(v.y, s.y)
            STAGE(v.z, s.z)
            STAGE(v.w, s.w)
#undef STAGE
        }
        __syncthreads();
        unsigned* outp = partials + (unsigned)g * NW;
        for (int i = tid; i < NW; i += NTHREADS) outp[i] = su.p1.h[i];
        if (tid < NBUCK) {
            su.p1.base[tid] = (int)atomicAdd(&gcur[tid], (unsigned)su.p1.lc[tid]);
            su.p1.lc[tid] = 0;            // reuse as flush rank cursor
        }
        __syncthreads();
        int ne = su.p1.ecnt;
        if (ne > EBCAP) ne = EBCAP;
        for (int j = tid; j < ne; j += NTHREADS) {
            unsigned e = su.p1.ebuf[j];
            int b = (int)(e >> 24);       // slot>>7
            int r = atomicAdd(&su.p1.lc[b], 1);
            unsigned pos = (unsigned)su.p1.base[b] + (unsigned)r;
            if (pos < (unsigned)((b + 1) << BCAP_SH)) bins[pos] = e;
        }
        // w -> bf16 conversion (no dinv): independent stream, overlaps hist.
        for (int k = gtid; k < N_NODES * 8; k += GSIZE) {
            float4 va = w4[k * 2];
            float4 vb = w4[k * 2 + 1];
            uint4 o;
            o.x = bfr(va.x) | (bfr(va.y) << 16);
            o.y = bfr(va.z) | (bfr(va.w) << 16);
            o.z = bfr(vb.x) | (bfr(vb.y) << 16);
            o.w = bfr(vb.z) | (bfr(vb.w) << 16);
            wh4[k] = o;
        }
    }
    __threadfence();
    grid.sync();

    // ---------------- P2: partials reduction -> dinv ----------------
    {
        int vb = blockIdx.x;
        if (vb < 196) {
            int wi = tid & 63, sg = tid >> 6;    // 64 words/block, 8 slice-groups
            int w = vb * 64 + wi;
            unsigned A = 0, B = 0, C = 0, D = 0;
            if (w < NW) {
                const unsigned* q = partials + w;
#pragma unroll
                for (int ch = 0; ch < 2; ++ch) {
                    unsigned x = 0, y = 0;
#pragma unroll
                    for (int k = 0; k < 16; ++k) {
                        unsigned v = q[(unsigned)(sg * 32 + ch * 16 + k) * NW];
                        x += v & 0x0F0F0F0Fu;
                        y += (v >> 4) & 0x0F0F0F0Fu;
                    }
                    A += x & 0x00FF00FFu;          // (n0, n4)
                    B += (x >> 8) & 0x00FF00FFu;   // (n2, n6)
                    C += y & 0x00FF00FFu;          // (n1, n5)
                    D += (y >> 8) & 0x00FF00FFu;   // (n3, n7)
                }
            }
            su.p2.pA[tid] = A; su.p2.pB[tid] = B; su.p2.pC[tid] = C; su.p2.pD[tid] = D;
            __syncthreads();
            if (tid < 64 && w < NW) {
                unsigned sA = 0, sB = 0, sC = 0, sD = 0;
#pragma unroll
                for (int k = 0; k < 8; ++k) {
                    sA += su.p2.pA[k * 64 + tid]; sB += su.p2.pB[k * 64 + tid];
                    sC += su.p2.pC[k * 64 + tid]; sD += su.p2.pD[k * 64 + tid];
                }
                float4 d0, d1;
                d0.x = rsqrtf((float)(sA & 0xFFFFu) + 1.0f);
                d0.y = rsqrtf((float)(sC & 0xFFFFu) + 1.0f);
                d0.z = rsqrtf((float)(sB & 0xFFFFu) + 1.0f);
                d0.w = rsqrtf((float)(sD & 0xFFFFu) + 1.0f);
                d1.x = rsqrtf((float)(sA >> 16) + 1.0f);
                d1.y = rsqrtf((float)(sC >> 16) + 1.0f);
                d1.z = rsqrtf((float)(sB >> 16) + 1.0f);
                d1.w = rsqrtf((float)(sD >> 16) + 1.0f);
                ((float4*)dinv)[w * 2] = d0;
                ((float4*)dinv)[w * 2 + 1] = d1;
            }
        }
    }
    __threadfence();
    grid.sync();

    // ---------------- P3: per-bucket sort + gather ----------------
    {
        int b = blockIdx.x;
        int cnt = (int)(gcur[b] - (unsigned)(b << BCAP_SH));
        if (cnt > BCAP) cnt = BCAP;
        const unsigned* bp = bins + ((unsigned)b << BCAP_SH);
        if (tid < 128) su.p3.lc[tid] = 0;
        __syncthreads();
        for (int j = tid; j < cnt; j += NTHREADS)
            atomicAdd(&su.p3.lc[(bp[j] >> 17) & 127], 1);
        __syncthreads();
        if (tid < 128) su.p3.st[tid] = su.p3.lc[tid];
        __syncthreads();
        for (int off = 1; off < 128; off <<= 1) {
            int v = (tid < 128 && tid >= off) ? su.p3.st[tid - off] : 0;
            __syncthreads();
            if (tid < 128) su.p3.st[tid] += v;
            __syncthreads();
        }
        if (tid < 128) {
            su.p3.st[tid] -= su.p3.lc[tid];   // exclusive start (preserved)
            su.p3.lc[tid] = su.p3.st[tid];    // scatter cursor; final = end
        }
        __syncthreads();
        for (int j = tid; j < cnt; j += NTHREADS) {
            unsigned e = bp[j];
            int r = atomicAdd(&su.p3.lc[(e >> 17) & 127], 1);
            su.p3.ebuf2[r] = e & 0x1FFFFu;
        }
        __syncthreads();
        int wave = tid >> 6;
        int rg = lane >> 3, dp = lane & 7;
#pragma unroll 1
        for (int q = 0; q < 16; ++q) {
            int sl = wave * 16 + q;
            int s0 = su.p3.st[sl];
            int cn = su.p3.lc[sl] - s0;
            double a0 = 0., a1 = 0., a2 = 0., a3 = 0., a4 = 0., a5 = 0., a6 = 0., a7 = 0.;
            int j = 0;
            for (; j + 16 <= cn; j += 16) {
                int e0 = (int)su.p3.ebuf2[s0 + j + rg];
                int e1 = (int)su.p3.ebuf2[s0 + j + 8 + rg];
                float dv0 = dinv[e0], dv1 = dinv[e1];
                uint4 oa = wh4[(e0 << 3) + dp];
                uint4 ob = wh4[(e1 << 3) + dp];
                a0 += (double)(bfx(oa.x) * dv0 + bfx(ob.x) * dv1);
                a1 += (double)(bfx(oa.x >> 16) * dv0 + bfx(ob.x >> 16) * dv1);
                a2 += (double)(bfx(oa.y) * dv0 + bfx(ob.y) * dv1);
                a3 += (double)(bfx(oa.y >> 16) * dv0 + bfx(ob.y >> 16) * dv1);
                a4 += (double)(bfx(oa.z) * dv0 + bfx(ob.z) * dv1);
                a5 += (double)(bfx(oa.z >> 16) * dv0 + bfx(ob.z >> 16) * dv1);
                a6 += (double)(bfx(oa.w) * dv0 + bfx(ob.w) * dv1);
                a7 += (double)(bfx(oa.w >> 16) * dv0 + bfx(ob.w >> 16) * dv1);
            }
            for (; j < cn; j += 8) {
                if (rg < cn - j) {
                    int e0 = (int)su.p3.ebuf2[s0 + j + rg];
                    float dv0 = dinv[e0];
                    uint4 oa = wh4[(e0 << 3) + dp];
                    a0 += (double)(bfx(oa.x) * dv0);
                    a1 += (double)(bfx(oa.x >> 16) * dv0);
                    a2 += (double)(bfx(oa.y) * dv0);
                    a3 += (double)(bfx(oa.y >> 16) * dv0);
                    a4 += (double)(bfx(oa.z) * dv0);
                    a5 += (double)(bfx(oa.z >> 16) * dv0);
                    a6 += (double)(bfx(oa.w) * dv0);
                    a7 += (double)(bfx(oa.w >> 16) * dv0);
                }
            }
#pragma unroll
            for (int m = 8; m <= 32; m <<= 1) {
                a0 += __shfl_xor(a0, m, 64); a1 += __shfl_xor(a1, m, 64);
                a2 += __shfl_xor(a2, m, 64); a3 += __shfl_xor(a3, m, 64);
                a4 += __shfl_xor(a4, m, 64); a5 += __shfl_xor(a5, m, 64);
                a6 += __shfl_xor(a6, m, 64); a7 += __shfl_xor(a7, m, 64);
            }
            if (rg == 0) {
                int gslot = (b << 7) + sl;
                int n = nodelist[gslot];
                float dn = dinv[n];
                uint4 u = wh4[(n << 3) + dp];
                float4 b0 = bias4[dp * 2], b1 = bias4[dp * 2 + 1];
                float r0 = ((float)a0 + bfx(u.x) * dn) * dn + b0.x;
                float r1 = ((float)a1 + bfx(u.x >> 16) * dn) * dn + b0.y;
                float r2 = ((float)a2 + bfx(u.y) * dn) * dn + b0.z;
                float r3 = ((float)a3 + bfx(u.y >> 16) * dn) * dn + b0.w;
                float r4 = ((float)a4 + bfx(u.z) * dn) * dn + b1.x;
                float r5 = ((float)a5 + bfx(u.z >> 16) * dn) * dn + b1.y;
                float r6 = ((float)a6 + bfx(u.w) * dn) * dn + b1.z;
                float r7 = ((float)a7 + bfx(u.w >> 16) * dn) * dn + b1.w;
                uint4 o;
                o.x = bfr(r0) | (bfr(r1) << 16);
                o.y = bfr(r2) | (bfr(r3) << 16);
                o.z = bfr(r4) | (bfr(r5) << 16);
                o.w = bfr(r6) | (bfr(r7) << 16);
                emb4[(gslot << 3) + dp] = o;
            }
        }
    }
    __threadfence();
    grid.sync();

    // ---------------- P4: FM pairwise + linear ----------------
    {
        const uint2* emb2 = (const uint2*)emb4;
        int li = tid & 15;
#pragma unroll
        for (int pass = 0; pass < 2; ++pass) {
            int p = pass * (GSIZE / 16) + (gtid >> 4);
            if (p < BATCH) {
                int a = pairs[p * 2], b = pairs[p * 2 + 1];
                int sa = (int)slot[a] - 1;
                int sb = (int)slot[b] - 1;
                uint2 ua = emb2[(sa << 4) + li];
                uint2 ub = emb2[(sb << 4) + li];
                float prod = bfx(ua.x) * bfx(ub.x) + bfx(ua.x >> 16) * bfx(ub.x >> 16)
                           + bfx(ua.y) * bfx(ub.y) + bfx(ua.y >> 16) * bfx(ub.y >> 16);
#pragma unroll
                for (int m = 1; m <= 8; m <<= 1) prod += __shfl_xor(prod, m, 64);
                if (li == 0) out[p] = lw[a] + lw[b] + lb[0] + prod;
            }
        }
    }
}

extern "C" void kernel_launch(void* const* d_in, const int* in_sizes, int n_in,
                              void* d_out, int out_size, void* d_ws, size_t ws_size,
                              hipStream_t stream) {
    const float* gcn_weight    = (const float*)d_in[0];
    const float* gcn_bias      = (const float*)d_in[1];
    const float* linear_weight = (const float*)d_in[2];
    const float* linear_bias   = (const float*)d_in[3];
    const int*   edge_index    = (const int*)d_in[4];
    const int*   pairs_p       = (const int*)d_in[5];
    float* out = (float*)d_out;

    char* ws = (char*)d_ws;
    unsigned* slot      = (unsigned*)(ws + OFF_SLOT);
    float*    dinv      = (float*)   (ws + OFF_DINV);
    int*      nodelist  = (int*)     (ws + OFF_NODELIST);
    unsigned* gcur      = (unsigned*)(ws + OFF_GCUR);
    unsigned* partials  = (unsigned*)(ws + OFF_PARTIALS);
    uint4*    wh4       = (uint4*)   (ws + OFF_WH);
    unsigned* bins      = (unsigned*)(ws + OFF_BINS);
    uint4*    emb4      = (uint4*)   (ws + OFF_EMB);

    const int* src_arr = edge_index;
    const int* dst_arr = edge_index + N_EDGES;
    const float4* w4f   = (const float4*)gcn_weight;
    const float4* bias4 = (const float4*)gcn_bias;

    void* args[] = {
        (void*)&pairs_p, (void*)&slot, (void*)&nodelist, (void*)&gcur,
        (void*)&src_arr, (void*)&dst_arr, (void*)&partials, (void*)&bins,
        (void*)&w4f, (void*)&dinv, (void*)&wh4, (void*)&bias4,
        (void*)&emb4, (void*)&linear_weight, (void*)&linear_bias, (void*)&out
    };
    hipLaunchCooperativeKernel((const void*)k_mega, dim3(NBLOCKS), dim3(NTHREADS),
                               args, 0, stream);
}

// Round 6
// 158.697 us; speedup vs baseline: 3.1354x; 3.1354x over previous
//
#include <hip/hip_runtime.h>

#define N_NODES 100000
#define N_EDGES 3200000
#define BATCH 16384
#define MAX_SLOTS 32768

// Nibble-packed degree histogram: 100K nodes x 4 bit = 50 KB LDS.
#define NW 12500       // words (8 nodes/word)
#define SLICES 256
#define EPS2 12500     // edges per slice
#define I4PS2 3125

// Bucket machinery: 256 buckets x 128 slots.
#define NBUCK 256
#define BCAP 8192      // entries per bucket region; mean fill 3493 -> +33 sigma
#define BCAP_SH 13
#define EBCAP 4608     // per-block LDS staging; mean 3493, sigma~50 -> +22 sigma

#define HIST_THREADS 1024
#define HGSIZE (SLICES * HIST_THREADS)

// Workspace layout (byte offsets, 16B aligned). ws_size = 256 MiB.
#define OFF_SLOT      0          // 100000 u32 (i+1 for winners; garbage elsewhere)
#define OFF_DINV      400000     // 100000 f32
#define OFF_NODELIST  800000     // 32768 ints (slot -> node, with duplicates)
#define OFF_GCUR      931072     // 256 u32 bucket cursors (init b<<13 in k_flags)
#define OFF_PARTIALS  932096     // 256 x 12500 words = 12.8 MB nibble degree counts
#define OFF_WH        13732096   // bf16(w), 100000x64x2 B = 12.8 MB (dinv NOT folded)
#define OFF_BINS      26532096   // packed (slot<<17|src), 256 x 8192 x 4 B = 8 MB
#define OFF_EMB       34920704   // bf16 32768x64

__device__ __forceinline__ unsigned bfr(float f) {   // fp32 -> bf16 bits, RNE
    unsigned u = __float_as_uint(f);
    return (u + 0x7FFFu + ((u >> 16) & 1u)) >> 16;
}
__device__ __forceinline__ float bfx(unsigned h) {   // low 16 bits -> fp32
    return __uint_as_float(h << 16);
}

// Slot assignment + bucket-cursor init. slot[n] races to one winner; all
// writers of slot[n] have pairs[i]==n, so any winner is valid. Loser slots get
// zero edges (cert certifies only the winner) and a self-term-only emb that
// k_final never reads.
__global__ void k_flags(const int* __restrict__ pairs, unsigned* __restrict__ slot,
                        int* __restrict__ nodelist, unsigned* __restrict__ gcur) {
    int i = blockIdx.x * blockDim.x + threadIdx.x;
    if (i < NBUCK) gcur[i] = (unsigned)(i << BCAP_SH);
    if (i < 2 * BATCH) {
        int n = pairs[i];
        nodelist[i] = n;
        slot[n] = (unsigned)(i + 1);
    }
}

// Certified needed-test: r=slot[d] valid iff (r-1)<32768 AND nodelist[r-1]==d.
__device__ __forceinline__ int cert(int d, const unsigned* __restrict__ slot,
                                    const int* __restrict__ nodelist) {
    unsigned r = slot[d];
    unsigned idx = r - 1u;
    if (idx < (unsigned)MAX_SLOTS && nodelist[idx] == d) return (int)idx;
    return -1;
}

// ONE edge pass (r4's measured-good structure) at 1024 threads (r5 lesson:
// the cert chain is latency-bound; 512 thr = 2 waves/SIMD was thin) + the
// w->bf16 conversion folded in (independent VMEM stream, overlaps the
// DS/latency-bound hist; frees k_mid to be reduction-only).
// NO per-edge global atomics (r1/r3: each costs ~43-53 B EA traffic).
__global__ void k_hist(const int* __restrict__ src, const int* __restrict__ dst,
                       const unsigned* __restrict__ slot, const int* __restrict__ nodelist,
                       unsigned* __restrict__ partials, unsigned* __restrict__ gcur,
                       unsigned* __restrict__ bins,
                       const float4* __restrict__ w4, uint4* __restrict__ wh4) {
    __shared__ unsigned h[NW];          // 50 KB
    __shared__ unsigned ebuf[EBCAP];    // 18 KB staged (slot<<17|src)
    __shared__ int lc[NBUCK];
    __shared__ int base[NBUCK];
    __shared__ int ecnt;
    int g = blockIdx.x;
    int tid = threadIdx.x;
    int lane = tid & 63;
    for (int i = tid; i < NW; i += HIST_THREADS) h[i] = 0;
    if (tid < NBUCK) lc[tid] = 0;
    if (tid == 0) ecnt = 0;
    __syncthreads();
    const int4* d4 = (const int4*)(dst + g * EPS2);
    const int4* s4 = (const int4*)(src + g * EPS2);
    for (int i = tid; i < I4PS2; i += HIST_THREADS) {
        int4 v = d4[i];
        int4 s = s4[i];
        atomicAdd(&h[v.x >> 3], 1u << ((v.x & 7) << 2));
        atomicAdd(&h[v.y >> 3], 1u << ((v.y & 7) << 2));
        atomicAdd(&h[v.z >> 3], 1u << ((v.z & 7) << 2));
        atomicAdd(&h[v.w >> 3], 1u << ((v.w & 7) << 2));
#define STAGE(dc, sc)                                                          \
        {                                                                      \
            int t = cert(dc, slot, nodelist);                                  \
            unsigned long long mk = __ballot(t >= 0);                          \
            int bs = 0;                                                        \
            if (lane == 0) bs = atomicAdd(&ecnt, (int)__popcll(mk));           \
            bs = __shfl(bs, 0, 64);                                            \
            if (t >= 0) {                                                      \
                int off = bs + (int)__popcll(mk & ((1ull << lane) - 1ull));    \
                if (off < EBCAP) {                                             \
                    ebuf[off] = ((unsigned)t << 17) | (unsigned)(sc);          \
                    atomicAdd(&lc[t >> 7], 1);                                 \
                }                                                              \
            }                                                                  \
        }
        STAGE(v.x, s.x)
        STAGE(v.y, s.y)
        STAGE(v.z, s.z)
        STAGE(v.w, s.w)
#undef STAGE
    }
    __syncthreads();
    unsigned* outp = partials + (unsigned)g * NW;
    for (int i = tid; i < NW; i += HIST_THREADS) outp[i] = h[i];
    if (tid < NBUCK) {
        base[tid] = (int)atomicAdd(&gcur[tid], (unsigned)lc[tid]);
        lc[tid] = 0;                      // reuse as flush rank cursor
    }
    __syncthreads();
    int ne = ecnt;
    if (ne > EBCAP) ne = EBCAP;
    for (int j = tid; j < ne; j += HIST_THREADS) {
        unsigned e = ebuf[j];
        int b = (int)(e >> 24);           // slot>>7
        int r = atomicAdd(&lc[b], 1);
        unsigned pos = (unsigned)base[b] + (unsigned)r;
        if (pos < (unsigned)((b + 1) << BCAP_SH)) bins[pos] = e;
    }
    // w -> bf16 conversion (no dinv): independent stream, overlaps the hist
    // phases across blocks/waves.
    for (int k = g * HIST_THREADS + tid; k < N_NODES * 8; k += HGSIZE) {
        float4 va = w4[k * 2];
        float4 vb = w4[k * 2 + 1];
        uint4 o;
        o.x = bfr(va.x) | (bfr(va.y) << 16);
        o.y = bfr(va.z) | (bfr(va.w) << 16);
        o.z = bfr(vb.x) | (bfr(vb.y) << 16);
        o.w = bfr(vb.z) | (bfr(vb.w) << 16);
        wh4[k] = o;
    }
}

// Reduction-only: nibble partials -> dinv (w conversion moved into k_hist).
__global__ void k_mid(const unsigned* __restrict__ partials, float* __restrict__ dinv) {
    __shared__ unsigned pA[256], pB[256], pC[256], pD[256];
    int blk = blockIdx.x;
    int wi = threadIdx.x & 31, sg = threadIdx.x >> 5;    // word-in-block, slice-group
    int w = blk * 32 + wi;
    unsigned A = 0, B = 0, C = 0, D = 0;
    if (w < NW) {
        const unsigned* q = partials + w;
#pragma unroll
        for (int ch = 0; ch < 2; ++ch) {                 // 2 chunks x 16 slices
            unsigned x = 0, y = 0;
#pragma unroll
            for (int k = 0; k < 16; ++k) {
                unsigned v = q[(unsigned)(sg * 32 + ch * 16 + k) * NW];
                x += v & 0x0F0F0F0Fu;
                y += (v >> 4) & 0x0F0F0F0Fu;
            }
            A += x & 0x00FF00FFu;          // (n0, n4)
            B += (x >> 8) & 0x00FF00FFu;   // (n2, n6)
            C += y & 0x00FF00FFu;          // (n1, n5)
            D += (y >> 8) & 0x00FF00FFu;   // (n3, n7)
        }
    }
    pA[threadIdx.x] = A; pB[threadIdx.x] = B; pC[threadIdx.x] = C; pD[threadIdx.x] = D;
    __syncthreads();
    if (threadIdx.x < 32 && w < NW) {
        unsigned sA = 0, sB = 0, sC = 0, sD = 0;
#pragma unroll
        for (int k = 0; k < 8; ++k) {
            sA += pA[k * 32 + wi]; sB += pB[k * 32 + wi];
            sC += pC[k * 32 + wi]; sD += pD[k * 32 + wi];
        }
        float4 d0, d1;
        d0.x = rsqrtf((float)(sA & 0xFFFFu) + 1.0f);
        d0.y = rsqrtf((float)(sC & 0xFFFFu) + 1.0f);
        d0.z = rsqrtf((float)(sB & 0xFFFFu) + 1.0f);
        d0.w = rsqrtf((float)(sD & 0xFFFFu) + 1.0f);
        d1.x = rsqrtf((float)(sA >> 16) + 1.0f);
        d1.y = rsqrtf((float)(sC >> 16) + 1.0f);
        d1.z = rsqrtf((float)(sB >> 16) + 1.0f);
        d1.w = rsqrtf((float)(sD >> 16) + 1.0f);
        ((float4*)dinv)[w * 2] = d0;
        ((float4*)dinv)[w * 2 + 1] = d1;
    }
}

// Fused counting-sort + gather. 2 blocks per bucket (r4 had 4: same 2048
// threads/CU co-residency at 1024 thr x 33.8 KB LDS, but redundant sort runs
// 2x not 4x). Each block sorts the bucket's ~3.5K entries in LDS, then its 16
// waves gather 64 of the 128 slots (4 slots/wave) with per-edge dinv[src]
// (wh holds bf16(w) only; math verified in r5). f64 accumulate keeps the
// race-ordered edge lists bit-stable.
__global__ void k_gfuse(const unsigned* __restrict__ gcur, const unsigned* __restrict__ bins,
                        const int* __restrict__ nodelist, const uint4* __restrict__ wh4,
                        const float* __restrict__ dinv, const float4* __restrict__ bias4,
                        uint4* __restrict__ emb4) {
    __shared__ unsigned ebuf2[BCAP];    // 32 KB sorted src ids
    __shared__ int lc[128], st[128];
    int b = blockIdx.x >> 1;
    int half = blockIdx.x & 1;
    int tid = threadIdx.x;
    int cnt = (int)(gcur[b] - (unsigned)(b << BCAP_SH));
    if (cnt > BCAP) cnt = BCAP;
    const unsigned* bp = bins + ((unsigned)b << BCAP_SH);
    if (tid < 128) lc[tid] = 0;
    __syncthreads();
    for (int j = tid; j < cnt; j += 1024) atomicAdd(&lc[(bp[j] >> 17) & 127], 1);
    __syncthreads();
    if (tid < 128) st[tid] = lc[tid];
    __syncthreads();
    for (int off = 1; off < 128; off <<= 1) {
        int v = (tid < 128 && tid >= off) ? st[tid - off] : 0;
        __syncthreads();
        if (tid < 128) st[tid] += v;
        __syncthreads();
    }
    if (tid < 128) {
        st[tid] -= lc[tid];               // exclusive start (preserved)
        lc[tid] = st[tid];                // scatter cursor; final value = end
    }
    __syncthreads();
    for (int j = tid; j < cnt; j += 1024) {
        unsigned e = bp[j];
        int r = atomicAdd(&lc[(e >> 17) & 127], 1);
        ebuf2[r] = e & 0x1FFFFu;
    }
    __syncthreads();
    int wave = tid >> 6, lane = tid & 63;
    int rg = lane >> 3, dp = lane & 7;
#pragma unroll 1
    for (int q = 0; q < 4; ++q) {
        int sl = half * 64 + wave * 4 + q;
        int s0 = st[sl];
        int cn = lc[sl] - s0;
        double a0 = 0., a1 = 0., a2 = 0., a3 = 0., a4 = 0., a5 = 0., a6 = 0., a7 = 0.;
        int j = 0;
        for (; j + 16 <= cn; j += 16) {
            int e0 = (int)ebuf2[s0 + j + rg];
            int e1 = (int)ebuf2[s0 + j + 8 + rg];
            float dv0 = dinv[e0], dv1 = dinv[e1];
            uint4 oa = wh4[(e0 << 3) + dp];
            uint4 ob = wh4[(e1 << 3) + dp];
            a0 += (double)(bfx(oa.x) * dv0 + bfx(ob.x) * dv1);
            a1 += (double)(bfx(oa.x >> 16) * dv0 + bfx(ob.x >> 16) * dv1);
            a2 += (double)(bfx(oa.y) * dv0 + bfx(ob.y) * dv1);
            a3 += (double)(bfx(oa.y >> 16) * dv0 + bfx(ob.y >> 16) * dv1);
            a4 += (double)(bfx(oa.z) * dv0 + bfx(ob.z) * dv1);
            a5 += (double)(bfx(oa.z >> 16) * dv0 + bfx(ob.z >> 16) * dv1);
            a6 += (double)(bfx(oa.w) * dv0 + bfx(ob.w) * dv1);
            a7 += (double)(bfx(oa.w >> 16) * dv0 + bfx(ob.w >> 16) * dv1);
        }
        for (; j < cn; j += 8) {
            if (rg < cn - j) {
                int e0 = (int)ebuf2[s0 + j + rg];
                float dv0 = dinv[e0];
                uint4 oa = wh4[(e0 << 3) + dp];
                a0 += (double)(bfx(oa.x) * dv0);
                a1 += (double)(bfx(oa.x >> 16) * dv0);
                a2 += (double)(bfx(oa.y) * dv0);
                a3 += (double)(bfx(oa.y >> 16) * dv0);
                a4 += (double)(bfx(oa.z) * dv0);
                a5 += (double)(bfx(oa.z >> 16) * dv0);
                a6 += (double)(bfx(oa.w) * dv0);
                a7 += (double)(bfx(oa.w >> 16) * dv0);
            }
        }
#pragma unroll
        for (int m = 8; m <= 32; m <<= 1) {
            a0 += __shfl_xor(a0, m, 64); a1 += __shfl_xor(a1, m, 64);
            a2 += __shfl_xor(a2, m, 64); a3 += __shfl_xor(a3, m, 64);
            a4 += __shfl_xor(a4, m, 64); a5 += __shfl_xor(a5, m, 64);
            a6 += __shfl_xor(a6, m, 64); a7 += __shfl_xor(a7, m, 64);
        }
        if (rg == 0) {
            int gslot = (b << 7) + sl;
            int n = nodelist[gslot];
            float dn = dinv[n];
            uint4 u = wh4[(n << 3) + dp];
            float4 b0 = bias4[dp * 2], b1 = bias4[dp * 2 + 1];
            float r0 = ((float)a0 + bfx(u.x) * dn) * dn + b0.x;
            float r1 = ((float)a1 + bfx(u.x >> 16) * dn) * dn + b0.y;
            float r2 = ((float)a2 + bfx(u.y) * dn) * dn + b0.z;
            float r3 = ((float)a3 + bfx(u.y >> 16) * dn) * dn + b0.w;
            float r4 = ((float)a4 + bfx(u.z) * dn) * dn + b1.x;
            float r5 = ((float)a5 + bfx(u.z >> 16) * dn) * dn + b1.y;
            float r6 = ((float)a6 + bfx(u.w) * dn) * dn + b1.z;
            float r7 = ((float)a7 + bfx(u.w >> 16) * dn) * dn + b1.w;
            uint4 o;
            o.x = bfr(r0) | (bfr(r1) << 16);
            o.y = bfr(r2) | (bfr(r3) << 16);
            o.z = bfr(r4) | (bfr(r5) << 16);
            o.w = bfr(r6) | (bfr(r7) << 16);
            emb4[(gslot << 3) + dp] = o;
        }
    }
}

// Four pairs per wave (16 lanes each), uint2 loads (4 dims/lane). slot[a] is
// always a winner id for pair nodes (written this launch by k_flags).
__global__ void k_final(const int* __restrict__ pairs, const unsigned* __restrict__ slot,
                        const uint2* __restrict__ emb2, const float* __restrict__ lw,
                        const float* __restrict__ lb, float* __restrict__ out) {
    int p = (blockIdx.x * blockDim.x + threadIdx.x) >> 4;
    int li = threadIdx.x & 15;
    if (p >= BATCH) return;
    int a = pairs[p * 2], b = pairs[p * 2 + 1];
    int sa = (int)slot[a] - 1;
    int sb = (int)slot[b] - 1;
    uint2 ua = emb2[(sa << 4) + li];
    uint2 ub = emb2[(sb << 4) + li];
    float prod = bfx(ua.x) * bfx(ub.x) + bfx(ua.x >> 16) * bfx(ub.x >> 16)
               + bfx(ua.y) * bfx(ub.y) + bfx(ua.y >> 16) * bfx(ub.y >> 16);
#pragma unroll
    for (int m = 1; m <= 8; m <<= 1) prod += __shfl_xor(prod, m, 64);
    if (li == 0) out[p] = lw[a] + lw[b] + lb[0] + prod;
}

extern "C" void kernel_launch(void* const* d_in, const int* in_sizes, int n_in,
                              void* d_out, int out_size, void* d_ws, size_t ws_size,
                              hipStream_t stream) {
    const float* gcn_weight    = (const float*)d_in[0];
    const float* gcn_bias      = (const float*)d_in[1];
    const float* linear_weight = (const float*)d_in[2];
    const float* linear_bias   = (const float*)d_in[3];
    const int*   edge_index    = (const int*)d_in[4];
    const int*   pairs         = (const int*)d_in[5];
    float* out = (float*)d_out;

    char* ws = (char*)d_ws;
    unsigned* slot      = (unsigned*)(ws + OFF_SLOT);
    float*    dinv      = (float*)   (ws + OFF_DINV);
    int*      nodelist  = (int*)     (ws + OFF_NODELIST);
    unsigned* gcur      = (unsigned*)(ws + OFF_GCUR);
    unsigned* partials  = (unsigned*)(ws + OFF_PARTIALS);
    uint4*    wh4       = (uint4*)   (ws + OFF_WH);
    unsigned* bins      = (unsigned*)(ws + OFF_BINS);
    uint4*    emb4      = (uint4*)   (ws + OFF_EMB);
    uint2*    emb2      = (uint2*)   (ws + OFF_EMB);

    const int* src_arr = edge_index;
    const int* dst_arr = edge_index + N_EDGES;

    k_flags<<<64, 512, 0, stream>>>(pairs, slot, nodelist, gcur);
    k_hist<<<SLICES, HIST_THREADS, 0, stream>>>(src_arr, dst_arr, slot, nodelist,
                                                partials, gcur, bins,
                                                (const float4*)gcn_weight, wh4);
    k_mid<<<391, 256, 0, stream>>>(partials, dinv);
    k_gfuse<<<NBUCK * 2, 1024, 0, stream>>>(gcur, bins, nodelist, wh4,
                                            dinv, (const float4*)gcn_bias, emb4);
    k_final<<<1024, 256, 0, stream>>>(pairs, slot, emb2, linear_weight, linear_bias, out);
}